// Round 5
// baseline (374.139 us; speedup 1.0000x reference)
//
#include <hip/hip_runtime.h>
#include <stdint.h>

// CIN (xDeepFM) forward, MI355X bf16-MFMA implementation. Round 5:
// Barrier-free K-loop — W (2.5MB) fits per-XCD L2, so read B-fragments
// DIRECTLY from global instead of LDS-staging them. Deletes wtile, all
// ds_writes, and both inner barriers; K-loop is a free-running stream of
// {2 global b128 loads -> A-gen VALU -> 8 MFMA}. Keeps round-4's proven
// skeleton: 512 blocks x 512 threads, 2 samples/block (M=64), 8 waves =
// 8 N-groups of 32 cols, acc[4][2], rbb/rdd row maps, sub[2] fsum.
// Layers: out[b,d,o] = relu(bias[o] + sum_{f,h'} x0[b,f,d]*h[b,h',d]*W[f*Hp+h',o])
//   layer0: Hp=39 (padded to 64), layers1/2: Hp=128. B=1024, F=39, D=32, N=256.

typedef __attribute__((ext_vector_type(8))) short short8;
typedef __attribute__((ext_vector_type(8))) unsigned short us8;
typedef __attribute__((ext_vector_type(4))) float f32x4;

__device__ __forceinline__ unsigned short f32_to_bf16(float f) {
  uint32_t u = __float_as_uint(f);
  return (unsigned short)((u + 0x7FFFu + ((u >> 16) & 1u)) >> 16);  // RNE
}
__device__ __forceinline__ float bf16_to_f32(unsigned short s) {
  return __uint_as_float(((uint32_t)s) << 16);
}
__device__ __forceinline__ uint32_t cvt_pk_bf16(float lo, float hi) {
  uint32_t r;
  asm("v_cvt_pk_bf16_f32 %0, %1, %2" : "=v"(r) : "v"(lo), "v"(hi));
  return r;
}

// ---------------- prep: W (K,256) f32  ->  WT (256, KPAD) bf16, transposed ----
__global__ void prep_wt(const float* __restrict__ W0, const float* __restrict__ W1,
                        const float* __restrict__ W2, unsigned short* __restrict__ WT0,
                        unsigned short* __restrict__ WT1, unsigned short* __restrict__ WT2) {
  int blk = blockIdx.x;
  const float* W;
  unsigned short* WT;
  int KPAD, kp0;
  bool l0 = false;
  if (blk < 312) { W = W0; WT = WT0; KPAD = 2496; kp0 = blk * 8; l0 = true; }
  else if (blk < 936) { W = W1; WT = WT1; KPAD = 4992; kp0 = (blk - 312) * 8; }
  else { W = W2; WT = WT2; KPAD = 4992; kp0 = (blk - 936) * 8; }

  __shared__ unsigned short lds[8][257];
  int t = threadIdx.x;  // 256 = n
  #pragma unroll
  for (int kk = 0; kk < 8; ++kk) {
    int kp = kp0 + kk;
    float v;
    if (l0) {
      int f = kp >> 6, hh = kp & 63;
      v = (hh < 39) ? W[(f * 39 + hh) * 256 + t] : 0.f;
    } else {
      v = W[kp * 256 + t];
    }
    lds[kk][t] = f32_to_bf16(v);
  }
  __syncthreads();
  us8 o;
  #pragma unroll
  for (int kk = 0; kk < 8; ++kk) o[kk] = lds[kk][t];
  *(us8*)(&WT[(size_t)t * KPAD + kp0]) = o;
}

// ---------------- main layer kernel ------------------------------------------
// grid 512 blocks x 512 threads. Block: 2 batch samples (M=64 rows = 2b x 32d),
// 8 waves as 8 N-groups (32 cols each); wave tile 64x32. No inner barriers.
template <int LAYER>
__global__ __launch_bounds__(512, 4) void cin_layer(
    const float* __restrict__ x, const unsigned short* __restrict__ hin,
    const unsigned short* __restrict__ WT, const float* __restrict__ bias,
    unsigned short* __restrict__ hout, float* __restrict__ fsum) {
  constexpr int HPAD = (LAYER == 0) ? 64 : 128;
  constexpr int HROW = HPAD + 8;
  constexpr int KPAD = 39 * HPAD;
  constexpr int HC = HPAD / 32;

  __shared__ __align__(16) unsigned short hT[2][32][HROW];  // h^T [b'][d][h']
  __shared__ __align__(16) unsigned short x0T[2][32][40];   // x0^T [b'][d][f]

  const int tid = threadIdx.x;
  const int bbase = blockIdx.x * 2;

  // ---- stage x0T (and hT for layer 0) from x (b,39,32) f32
  for (int idx = tid; idx < 2 * 1248; idx += 512) {
    int b = idx / 1248;
    int rem = idx - b * 1248;
    int f = rem >> 5, d = rem & 31;
    unsigned short us = f32_to_bf16(x[(bbase + b) * 1248 + rem]);
    x0T[b][d][f] = us;
    if (LAYER == 0) hT[b][d][f] = us;
  }
  if (LAYER == 0) {
    for (int idx = tid; idx < 2 * 32 * 25; idx += 512) {  // zero h' in [39,64)
      int b = idx / 800;
      int rem = idx - b * 800;
      int d = rem / 25, p = rem - d * 25;
      hT[b][d][39 + p] = 0;
    }
  } else {
    for (int idx = tid; idx < 2 * 32 * 16; idx += 512) {  // copy h_buf bf16 [b][d][128]
      int b = idx >> 9, rem = idx & 511;
      int d = rem >> 4, c = rem & 15;
      us8 v = *(const us8*)(&hin[(((bbase + b) * 32 + d) << 7) + c * 8]);
      *(us8*)(&hT[b][d][c * 8]) = v;
    }
  }

  const int lane = tid & 63;
  const int w = tid >> 6;  // 0..7
  const int wx = w;        // N-group (32 cols each)
  const int l15 = lane & 15;
  const int g = lane >> 4;

  f32x4 acc[4][2];
  #pragma unroll
  for (int i = 0; i < 4; ++i)
    #pragma unroll
    for (int j = 0; j < 2; ++j) acc[i][j] = (f32x4){0.f, 0.f, 0.f, 0.f};

  int rbb[4], rdd[4];  // per m-tile: which b' and d this lane's A-row maps to
  #pragma unroll
  for (int mt = 0; mt < 4; ++mt) {
    int row = mt * 16 + l15;
    rbb[mt] = row >> 5;
    rdd[mt] = row & 31;
  }

  // Direct-from-global B pointers (same per-lane k-map as A => layout-safe):
  // B[n][k] fragment for this lane: WT[n*KPAD + kb + g*8], n = wx*32 + nt*16 + l15
  const unsigned short* wp0 = WT + (size_t)(wx * 32 + 0 * 16 + l15) * KPAD + g * 8;
  const unsigned short* wp1 = WT + (size_t)(wx * 32 + 1 * 16 + l15) * KPAD + g * 8;

  __syncthreads();  // covers hT/x0T staging (the only barrier in the kernel)

  float hf[4][8];  // unpacked h fragment (per m-tile), reused across the f loop
  for (int hc = 0; hc < HC; ++hc) {
    #pragma unroll
    for (int mt = 0; mt < 4; ++mt) {
      us8 h8 = *(const us8*)(&hT[rbb[mt]][rdd[mt]][hc * 32 + g * 8]);
      #pragma unroll
      for (int e = 0; e < 8; ++e) hf[mt][e] = bf16_to_f32(h8[e]);
    }
    for (int f = 0; f < 39; ++f) {
      const int kb = f * HPAD + hc * 32;
      // issue B loads first (L2 latency hides under A-gen VALU)
      union { us8 u; short8 v; } bu0, bu1;
      bu0.u = *(const us8*)(wp0 + kb);
      bu1.u = *(const us8*)(wp1 + kb);
      // A fragments: a[k] = bf16(x0[b,f,d] * h[b,k,d])
      short8 afr[4];
      #pragma unroll
      for (int mt = 0; mt < 4; ++mt) {
        float xs = bf16_to_f32(x0T[rbb[mt]][rdd[mt]][f]);
        union { uint32_t u[4]; short8 v; } au;
        #pragma unroll
        for (int i = 0; i < 4; ++i)
          au.u[i] = cvt_pk_bf16(hf[mt][2 * i] * xs, hf[mt][2 * i + 1] * xs);
        afr[mt] = au.v;
      }
      #pragma unroll
      for (int mt = 0; mt < 4; ++mt) {
        acc[mt][0] = __builtin_amdgcn_mfma_f32_16x16x32_bf16(afr[mt], bu0.v, acc[mt][0], 0, 0, 0);
        acc[mt][1] = __builtin_amdgcn_mfma_f32_16x16x32_bf16(afr[mt], bu1.v, acc[mt][1], 0, 0, 0);
      }
    }
  }

  // ---- epilogue: relu(acc+bias); o<128 -> h for next layer; else d-sums -> fsum
  float bv[2];
  #pragma unroll
  for (int nt = 0; nt < 2; ++nt) bv[nt] = bias[wx * 32 + nt * 16 + l15];

  if (LAYER < 2 && wx < 4) {  // h half (o in [0,128))
    #pragma unroll
    for (int mt = 0; mt < 4; ++mt) {
      #pragma unroll
      for (int nt = 0; nt < 2; ++nt) {
        int o = wx * 32 + nt * 16 + l15;
        #pragma unroll
        for (int r = 0; r < 4; ++r) {
          int row = mt * 16 + g * 4 + r;  // C/D: row=(lane>>4)*4+reg, col=lane&15
          int bb = row >> 5, dd = row & 31;
          float v = fmaxf(acc[mt][nt][r] + bv[nt], 0.f);
          hout[(((bbase + bb) * 32 + dd) << 7) + o] = f32_to_bf16(v);
        }
      }
    }
  } else {  // finals: sum over d, store to fsum[b][j]
    #pragma unroll
    for (int nt = 0; nt < 2; ++nt) {
      float sub[2] = {0.f, 0.f};  // per sample within this wave's 64 rows
      #pragma unroll
      for (int mt = 0; mt < 4; ++mt) {
        #pragma unroll
        for (int r = 0; r < 4; ++r) {
          float v = fmaxf(acc[mt][nt][r] + bv[nt], 0.f);
          sub[mt >> 1] += v;
        }
      }
      #pragma unroll
      for (int h = 0; h < 2; ++h) {
        sub[h] += __shfl_xor(sub[h], 16);
        sub[h] += __shfl_xor(sub[h], 32);
      }
      if (lane < 16) {
        int o = wx * 32 + nt * 16 + l15;
        int j = (LAYER == 0) ? (o - 128) : ((LAYER == 1) ? o : (256 + o));
        fsum[bbase * 512 + j] = sub[0];
        fsum[(bbase + 1) * 512 + j] = sub[1];
      }
    }
  }
}

// ---------------- finalize: out[b] = fc_b + sum_j fsum[b][j]*fc_w[j] ----------
__global__ void finalize(const float* __restrict__ fsum, const float* __restrict__ fc_w,
                         const float* __restrict__ fc_b, float* __restrict__ out) {
  int b = blockIdx.x;
  int lane = threadIdx.x;  // 64
  const float* fs = fsum + (size_t)b * 512;
  float s = 0.f;
  #pragma unroll
  for (int k = 0; k < 8; ++k) {
    int j = k * 64 + lane;
    s += fs[j] * fc_w[j];
  }
  #pragma unroll
  for (int off = 32; off; off >>= 1) s += __shfl_xor(s, off);
  if (lane == 0) out[b] = s + fc_b[0];
}

extern "C" void kernel_launch(void* const* d_in, const int* in_sizes, int n_in,
                              void* d_out, int out_size, void* d_ws, size_t ws_size,
                              hipStream_t stream) {
  const float* x = (const float*)d_in[0];
  const float* W0 = (const float*)d_in[1];
  const float* b0 = (const float*)d_in[2];
  const float* W1 = (const float*)d_in[3];
  const float* b1 = (const float*)d_in[4];
  const float* W2 = (const float*)d_in[5];
  const float* b2 = (const float*)d_in[6];
  const float* fc_w = (const float*)d_in[7];
  const float* fc_b = (const float*)d_in[8];
  float* out = (float*)d_out;

  char* ws = (char*)d_ws;
  size_t oWT0 = 0;
  size_t oWT1 = oWT0 + (size_t)256 * 2496 * 2;
  size_t oWT2 = oWT1 + (size_t)256 * 4992 * 2;
  size_t oH = oWT2 + (size_t)256 * 4992 * 2;
  size_t oFS = oH + (size_t)1024 * 32 * 128 * 2;
  unsigned short* WT0 = (unsigned short*)(ws + oWT0);
  unsigned short* WT1 = (unsigned short*)(ws + oWT1);
  unsigned short* WT2 = (unsigned short*)(ws + oWT2);
  unsigned short* hbuf = (unsigned short*)(ws + oH);
  float* fsum = (float*)(ws + oFS);

  prep_wt<<<1560, 256, 0, stream>>>(W0, W1, W2, WT0, WT1, WT2);
  cin_layer<0><<<512, 512, 0, stream>>>(x, nullptr, WT0, b0, hbuf, fsum);
  cin_layer<1><<<512, 512, 0, stream>>>(x, hbuf, WT1, b1, hbuf, fsum);
  cin_layer<2><<<512, 512, 0, stream>>>(x, hbuf, WT2, b2, nullptr, fsum);
  finalize<<<1024, 64, 0, stream>>>(fsum, fc_w, fc_b, out);
}

// Round 6
// 235.716 us; speedup vs baseline: 1.5872x; 1.5872x over previous
//
#include <hip/hip_runtime.h>
#include <stdint.h>

// CIN (xDeepFM) forward, MI355X f16-MFMA implementation. Round 6:
//  - global_load_lds(16B) async W staging, K_TILE=64, dbuf, ONE barrier/tile
//  - XOR-swizzled wtile (linear LDS dest + inverse-swizzled global source +
//    swizzled read) -> conflict-free ds_read_b128 B-fragments
//  - f16 everywhere: A-gen = 4 v_pk_mul_f16 per m-tile (x0 pre-packed (x,x))
//  - wave tile m_t=8 (all 128 block rows) x n_t=2 (32 cols); 8 waves cover
//    N=256; grid 256 = 1 block/CU; 512 threads.
// Layers: out[b,d,o] = relu(bias[o] + sum_{f,h'} x0[b,f,d]*h[b,h',d]*W[f*Hp+h',o])
//   layer0: Hp=39 (pad 64), layers1/2: Hp=128. B=1024, F=39, D=32, N=256.

typedef unsigned int u32;
typedef unsigned short u16;
typedef __attribute__((ext_vector_type(8))) unsigned short us8;
typedef __attribute__((ext_vector_type(8))) _Float16 half8;
typedef __attribute__((ext_vector_type(4))) float f32x4;

__device__ __forceinline__ u16 f32_to_f16u(float f) {
  union { _Float16 h; u16 u; } c;
  c.h = (_Float16)f;
  return c.u;
}
__device__ __forceinline__ u32 pkmul(u32 a, u32 b) {
  u32 r;
  asm("v_pk_mul_f16 %0, %1, %2" : "=v"(r) : "v"(a), "v"(b));
  return r;
}
__device__ __forceinline__ void gload16(const u16* g, u16* l) {
  __builtin_amdgcn_global_load_lds((const __attribute__((address_space(1))) u32*)g,
                                   (__attribute__((address_space(3))) u32*)l, 16, 0, 0);
}

// ---------------- prep: W (K,256) f32 -> WT (256, KPAD) f16, transposed ------
__global__ void prep_wt(const float* __restrict__ W0, const float* __restrict__ W1,
                        const float* __restrict__ W2, u16* __restrict__ WT0,
                        u16* __restrict__ WT1, u16* __restrict__ WT2) {
  int blk = blockIdx.x;
  const float* W;
  u16* WT;
  int KPAD, kp0;
  bool l0 = false;
  if (blk < 312) { W = W0; WT = WT0; KPAD = 2496; kp0 = blk * 8; l0 = true; }
  else if (blk < 936) { W = W1; WT = WT1; KPAD = 4992; kp0 = (blk - 312) * 8; }
  else { W = W2; WT = WT2; KPAD = 4992; kp0 = (blk - 936) * 8; }

  __shared__ u16 lds[8][257];
  int t = threadIdx.x;  // 256 = n
  #pragma unroll
  for (int kk = 0; kk < 8; ++kk) {
    int kp = kp0 + kk;
    float v;
    if (l0) {
      int f = kp >> 6, hh = kp & 63;
      v = (hh < 39) ? W[(f * 39 + hh) * 256 + t] : 0.f;
    } else {
      v = W[kp * 256 + t];
    }
    lds[kk][t] = f32_to_f16u(v);
  }
  __syncthreads();
  us8 o;
  #pragma unroll
  for (int kk = 0; kk < 8; ++kk) o[kk] = lds[kk][t];
  *(us8*)(&WT[(size_t)t * KPAD + kp0]) = o;
}

// ---------------- main layer kernel ------------------------------------------
// grid 256 x 512 threads. Block: 4 samples (M=128 rows), 8 waves each covering
// all 128 rows x its own 32-col slice. K-tile = 64 (2 k32 steps), dbuf LDS.
template <int LAYER>
__global__ __launch_bounds__(512, 2) void cin_layer(
    const float* __restrict__ x, const u16* __restrict__ hin,
    const u16* __restrict__ WT, const float* __restrict__ bias,
    u16* __restrict__ hout, float* __restrict__ fsum) {
  constexpr int HPAD = (LAYER == 0) ? 64 : 128;
  constexpr int HROW = HPAD + 8;
  constexpr int KPAD = 39 * HPAD;
  constexpr int HC2 = HPAD / 64;  // k64 tiles per f
  constexpr int NT = 39 * HC2;

  __shared__ __align__(16) u16 wtile[2][256 * 64];  // [n][64k] swizzled, dbuf
  __shared__ __align__(16) u16 hT[4][32][HROW];     // h^T f16 [b'][d][h']
  __shared__ u32 x0pk[4][32][41];                   // (x,x) packed f16 pairs

  const int tid = threadIdx.x;
  const int bbase = blockIdx.x * 4;

  // ---- stage x -> x0pk (+hT for layer 0)
  for (int idx = tid; idx < 4 * 1248; idx += 512) {
    int b = idx / 1248;
    int rem = idx - b * 1248;
    int f = rem >> 5, d = rem & 31;
    u16 xh = f32_to_f16u(x[(bbase + b) * 1248 + rem]);
    x0pk[b][d][f] = (u32)xh | ((u32)xh << 16);
    if (LAYER == 0) hT[b][d][f] = xh;
  }
  if (LAYER == 0) {
    for (int idx = tid; idx < 4 * 32 * 25; idx += 512) {  // zero h' in [39,64)
      int b = idx / 800;
      int rem = idx - b * 800;
      int d = rem / 25, p = rem - d * 25;
      hT[b][d][39 + p] = 0;
    }
  } else {
    for (int idx = tid; idx < 4 * 32 * 16; idx += 512) {  // h_buf f16 [b][d][128]
      int b = idx >> 9, rem = idx & 511;
      int d = rem >> 4, c = rem & 15;
      us8 v = *(const us8*)(&hin[(((bbase + b) * 32 + d) << 7) + c * 8]);
      *(us8*)(&hT[b][d][c * 8]) = v;
    }
  }

  const int lane = tid & 63;
  const int w = tid >> 6;  // wave 0..7 -> 32-col slice
  const int l15 = lane & 15;
  const int g = lane >> 4;

  // staging per-lane source (inverse-swizzle): lane covers row n, 16B slot
  const int nloc = lane >> 3, slot = lane & 7;
  const int qq = slot ^ nloc;          // data chunk index held at this slot
  const int cp = qq >> 2, kcp = qq & 3;
  const u16* wsrc = WT + (size_t)(w * 32 + nloc) * KPAD + cp * 32 + kcp * 8;

  // B-read bases (swizzled): row n = w*32 + nt*16 + l15, n&7 == l15&7
  const int xorm = (l15 & 7) * 8;          // u16 units
  const int rB0 = (w * 32 + l15) * 64;     // nt=0 row base

  f32x4 acc[8][2];
  #pragma unroll
  for (int m = 0; m < 8; ++m)
    #pragma unroll
    for (int n = 0; n < 2; ++n) acc[m][n] = (f32x4){0.f, 0.f, 0.f, 0.f};

  // prologue: stage tile 0 (koff=0) into buf 0
  {
    u16* dst = &wtile[0][(w * 32) * 64];
    #pragma unroll
    for (int j = 0; j < 4; ++j) gload16(wsrc + (size_t)j * 8 * KPAD, dst + j * 8 * 64);
  }
  __syncthreads();  // covers hT/x0pk ds-writes AND tile0 (vmcnt0+lgkmcnt0)

  union HF { u32 u[4]; half8 h; us8 s; };
  int tt = 0;
  for (int t = 0; t < HC2; ++t) {
    HF hf2[8][2];  // h fragments for hc = 2t, 2t+1 (reused across all f)
    #pragma unroll
    for (int m = 0; m < 8; ++m)
      #pragma unroll
      for (int c = 0; c < 2; ++c)
        hf2[m][c].s = *(const us8*)(&hT[m >> 1][(m & 1) * 16 + l15][(2 * t + c) * 32 + g * 8]);
    for (int f = 0; f < 39; ++f, ++tt) {
      const int buf = tt & 1;
      if (tt + 1 < NT) {  // async-stage next tile into buf^1
        const int nf = (f + 1 < 39) ? f + 1 : 0;
        const int ntp = (f + 1 < 39) ? t : t + 1;
        const int koff = nf * HPAD + ntp * 64;
        u16* dst = &wtile[buf ^ 1][(w * 32) * 64];
        #pragma unroll
        for (int j = 0; j < 4; ++j)
          gload16(wsrc + (size_t)j * 8 * KPAD + koff, dst + j * 8 * 64);
      }
      u32 xs[8];
      #pragma unroll
      for (int m = 0; m < 8; ++m) xs[m] = x0pk[m >> 1][(m & 1) * 16 + l15][f];
      #pragma unroll
      for (int c = 0; c < 2; ++c) {
        const int off = (c * 32 + g * 8) ^ xorm;
        HF b0, b1;
        b0.s = *(const us8*)(&wtile[buf][rB0 + off]);
        b1.s = *(const us8*)(&wtile[buf][rB0 + 16 * 64 + off]);
        #pragma unroll
        for (int m = 0; m < 8; ++m) {
          HF a;
          #pragma unroll
          for (int i = 0; i < 4; ++i) a.u[i] = pkmul(hf2[m][c].u[i], xs[m]);
          acc[m][0] = __builtin_amdgcn_mfma_f32_16x16x32_f16(a.h, b0.h, acc[m][0], 0, 0, 0);
          acc[m][1] = __builtin_amdgcn_mfma_f32_16x16x32_f16(a.h, b1.h, acc[m][1], 0, 0, 0);
        }
      }
      __syncthreads();  // single barrier: buf reads done; buf^1 loads drained
    }
  }

  // ---- epilogue: relu(acc+bias); o<128 -> h for next layer; else d-sums
  float bv[2];
  #pragma unroll
  for (int nt = 0; nt < 2; ++nt) bv[nt] = bias[w * 32 + nt * 16 + l15];

  if (LAYER < 2 && w < 4) {  // h half (o in [0,128))
    #pragma unroll
    for (int m = 0; m < 8; ++m)
      #pragma unroll
      for (int nt = 0; nt < 2; ++nt) {
        int o = w * 32 + nt * 16 + l15;
        #pragma unroll
        for (int r = 0; r < 4; ++r) {
          int row = m * 16 + g * 4 + r;  // C/D: row=(lane>>4)*4+reg, col=lane&15
          int s = row >> 5, d = row & 31;
          float v = fmaxf(acc[m][nt][r] + bv[nt], 0.f);
          hout[(((bbase + s) * 32 + d) << 7) + o] = f32_to_f16u(v);
        }
      }
  } else {  // finals: sum over d per sample, store fsum[b][j]
    #pragma unroll
    for (int nt = 0; nt < 2; ++nt) {
      float sub[4] = {0.f, 0.f, 0.f, 0.f};
      #pragma unroll
      for (int m = 0; m < 8; ++m)
        #pragma unroll
        for (int r = 0; r < 4; ++r)
          sub[m >> 1] += fmaxf(acc[m][nt][r] + bv[nt], 0.f);
      #pragma unroll
      for (int s = 0; s < 4; ++s) {
        sub[s] += __shfl_xor(sub[s], 16);
        sub[s] += __shfl_xor(sub[s], 32);
      }
      if (lane < 16) {
        int o = w * 32 + nt * 16 + l15;
        int j = (LAYER == 0) ? (o - 128) : ((LAYER == 1) ? o : (256 + o));
        #pragma unroll
        for (int s = 0; s < 4; ++s) fsum[(bbase + s) * 512 + j] = sub[s];
      }
    }
  }
}

// ---------------- finalize: out[b] = fc_b + sum_j fsum[b][j]*fc_w[j] ----------
__global__ void finalize(const float* __restrict__ fsum, const float* __restrict__ fc_w,
                         const float* __restrict__ fc_b, float* __restrict__ out) {
  int b = blockIdx.x;
  int lane = threadIdx.x;  // 64
  const float* fs = fsum + (size_t)b * 512;
  float s = 0.f;
  #pragma unroll
  for (int k = 0; k < 8; ++k) {
    int j = k * 64 + lane;
    s += fs[j] * fc_w[j];
  }
  #pragma unroll
  for (int off = 32; off; off >>= 1) s += __shfl_xor(s, off);
  if (lane == 0) out[b] = s + fc_b[0];
}

extern "C" void kernel_launch(void* const* d_in, const int* in_sizes, int n_in,
                              void* d_out, int out_size, void* d_ws, size_t ws_size,
                              hipStream_t stream) {
  const float* x = (const float*)d_in[0];
  const float* W0 = (const float*)d_in[1];
  const float* b0 = (const float*)d_in[2];
  const float* W1 = (const float*)d_in[3];
  const float* b1 = (const float*)d_in[4];
  const float* W2 = (const float*)d_in[5];
  const float* b2 = (const float*)d_in[6];
  const float* fc_w = (const float*)d_in[7];
  const float* fc_b = (const float*)d_in[8];
  float* out = (float*)d_out;

  char* ws = (char*)d_ws;
  size_t oWT0 = 0;
  size_t oWT1 = oWT0 + (size_t)256 * 2496 * 2;
  size_t oWT2 = oWT1 + (size_t)256 * 4992 * 2;
  size_t oH = oWT2 + (size_t)256 * 4992 * 2;
  size_t oFS = oH + (size_t)1024 * 32 * 128 * 2;
  u16* WT0 = (u16*)(ws + oWT0);
  u16* WT1 = (u16*)(ws + oWT1);
  u16* WT2 = (u16*)(ws + oWT2);
  u16* hbuf = (u16*)(ws + oH);
  float* fsum = (float*)(ws + oFS);

  prep_wt<<<1560, 256, 0, stream>>>(W0, W1, W2, WT0, WT1, WT2);
  cin_layer<0><<<256, 512, 0, stream>>>(x, nullptr, WT0, b0, hbuf, fsum);
  cin_layer<1><<<256, 512, 0, stream>>>(x, hbuf, WT1, b1, hbuf, fsum);
  cin_layer<2><<<256, 512, 0, stream>>>(x, hbuf, WT2, b2, nullptr, fsum);
  finalize<<<1024, 64, 0, stream>>>(fsum, fc_w, fc_b, out);
}

// Round 7
// 200.236 us; speedup vs baseline: 1.8685x; 1.1772x over previous
//
#include <hip/hip_runtime.h>
#include <stdint.h>

// CIN (xDeepFM) forward, MI355X f16-MFMA implementation. Round 7:
//  - BARRIER-FREE K-loop: wtile slices are per-wave-private (wave w stages and
//    reads only rows [w*32,w*32+32)), so the per-iteration __syncthreads is
//    replaced by per-wave counted s_waitcnt vmcnt(4) + sched_barrier(0).
//    Loads for tile t+1 issue first; wait covers only tile t's 4 loads (T4).
//  - everything else identical to round 6 (proven): global_load_lds(16B)
//    staging, XOR-swizzled wtile, f16 A-gen via v_pk_mul_f16, m_t=8 x n_t=2,
//    grid 256 x 512 threads.
// Layers: out[b,d,o] = relu(bias[o] + sum_{f,h'} x0[b,f,d]*h[b,h',d]*W[f*Hp+h',o])
//   layer0: Hp=39 (pad 64), layers1/2: Hp=128. B=1024, F=39, D=32, N=256.

typedef unsigned int u32;
typedef unsigned short u16;
typedef __attribute__((ext_vector_type(8))) unsigned short us8;
typedef __attribute__((ext_vector_type(8))) _Float16 half8;
typedef __attribute__((ext_vector_type(4))) float f32x4;

__device__ __forceinline__ u16 f32_to_f16u(float f) {
  union { _Float16 h; u16 u; } c;
  c.h = (_Float16)f;
  return c.u;
}
__device__ __forceinline__ u32 pkmul(u32 a, u32 b) {
  u32 r;
  asm("v_pk_mul_f16 %0, %1, %2" : "=v"(r) : "v"(a), "v"(b));
  return r;
}
__device__ __forceinline__ void gload16(const u16* g, u16* l) {
  __builtin_amdgcn_global_load_lds((const __attribute__((address_space(1))) u32*)g,
                                   (__attribute__((address_space(3))) u32*)l, 16, 0, 0);
}
__device__ __forceinline__ void wait_vm4() {
  asm volatile("s_waitcnt vmcnt(4)" ::: "memory");
  __builtin_amdgcn_sched_barrier(0);
}
__device__ __forceinline__ void wait_vm0() {
  asm volatile("s_waitcnt vmcnt(0)" ::: "memory");
  __builtin_amdgcn_sched_barrier(0);
}

// ---------------- prep: W (K,256) f32 -> WT (256, KPAD) f16, transposed ------
__global__ void prep_wt(const float* __restrict__ W0, const float* __restrict__ W1,
                        const float* __restrict__ W2, u16* __restrict__ WT0,
                        u16* __restrict__ WT1, u16* __restrict__ WT2) {
  int blk = blockIdx.x;
  const float* W;
  u16* WT;
  int KPAD, kp0;
  bool l0 = false;
  if (blk < 312) { W = W0; WT = WT0; KPAD = 2496; kp0 = blk * 8; l0 = true; }
  else if (blk < 936) { W = W1; WT = WT1; KPAD = 4992; kp0 = (blk - 312) * 8; }
  else { W = W2; WT = WT2; KPAD = 4992; kp0 = (blk - 936) * 8; }

  __shared__ u16 lds[8][257];
  int t = threadIdx.x;  // 256 = n
  #pragma unroll
  for (int kk = 0; kk < 8; ++kk) {
    int kp = kp0 + kk;
    float v;
    if (l0) {
      int f = kp >> 6, hh = kp & 63;
      v = (hh < 39) ? W[(f * 39 + hh) * 256 + t] : 0.f;
    } else {
      v = W[kp * 256 + t];
    }
    lds[kk][t] = f32_to_f16u(v);
  }
  __syncthreads();
  us8 o;
  #pragma unroll
  for (int kk = 0; kk < 8; ++kk) o[kk] = lds[kk][t];
  *(us8*)(&WT[(size_t)t * KPAD + kp0]) = o;
}

// ---------------- main layer kernel ------------------------------------------
// grid 256 x 512 threads. Block: 4 samples (M=128 rows), 8 waves each covering
// all 128 rows x its own 32-col slice. K-tile = 64, dbuf LDS, no inner barriers.
template <int LAYER>
__global__ __launch_bounds__(512, 2) void cin_layer(
    const float* __restrict__ x, const u16* __restrict__ hin,
    const u16* __restrict__ WT, const float* __restrict__ bias,
    u16* __restrict__ hout, float* __restrict__ fsum) {
  constexpr int HPAD = (LAYER == 0) ? 64 : 128;
  constexpr int HROW = HPAD + 8;
  constexpr int KPAD = 39 * HPAD;
  constexpr int HC2 = HPAD / 64;  // k64 tiles per f
  constexpr int NT = 39 * HC2;

  __shared__ __align__(16) u16 wtile[2][256 * 64];  // [n][64k] swizzled, dbuf
  __shared__ __align__(16) u16 hT[4][32][HROW];     // h^T f16 [b'][d][h']
  __shared__ u32 x0pk[4][32][41];                   // (x,x) packed f16 pairs

  const int tid = threadIdx.x;
  const int bbase = blockIdx.x * 4;

  // ---- stage x -> x0pk (+hT for layer 0)
  for (int idx = tid; idx < 4 * 1248; idx += 512) {
    int b = idx / 1248;
    int rem = idx - b * 1248;
    int f = rem >> 5, d = rem & 31;
    u16 xh = f32_to_f16u(x[(bbase + b) * 1248 + rem]);
    x0pk[b][d][f] = (u32)xh | ((u32)xh << 16);
    if (LAYER == 0) hT[b][d][f] = xh;
  }
  if (LAYER == 0) {
    for (int idx = tid; idx < 4 * 32 * 25; idx += 512) {  // zero h' in [39,64)
      int b = idx / 800;
      int rem = idx - b * 800;
      int d = rem / 25, p = rem - d * 25;
      hT[b][d][39 + p] = 0;
    }
  } else {
    for (int idx = tid; idx < 4 * 32 * 16; idx += 512) {  // h_buf f16 [b][d][128]
      int b = idx >> 9, rem = idx & 511;
      int d = rem >> 4, c = rem & 15;
      us8 v = *(const us8*)(&hin[(((bbase + b) * 32 + d) << 7) + c * 8]);
      *(us8*)(&hT[b][d][c * 8]) = v;
    }
  }

  const int lane = tid & 63;
  const int w = tid >> 6;  // wave 0..7 -> 32-col slice
  const int l15 = lane & 15;
  const int g = lane >> 4;

  // staging per-lane source (inverse-swizzle): lane covers row n, 16B slot
  const int nloc = lane >> 3, slot = lane & 7;
  const int qq = slot ^ nloc;          // data chunk index held at this slot
  const int cp = qq >> 2, kcp = qq & 3;
  const u16* wsrc = WT + (size_t)(w * 32 + nloc) * KPAD + cp * 32 + kcp * 8;

  // B-read bases (swizzled): row n = w*32 + nt*16 + l15, n&7 == l15&7
  const int xorm = (l15 & 7) * 8;          // u16 units
  const int rB0 = (w * 32 + l15) * 64;     // nt=0 row base

  f32x4 acc[8][2];
  #pragma unroll
  for (int m = 0; m < 8; ++m)
    #pragma unroll
    for (int n = 0; n < 2; ++n) acc[m][n] = (f32x4){0.f, 0.f, 0.f, 0.f};

  // prologue: stage tile 0 (koff=0) into buf 0
  {
    u16* dst = &wtile[0][(w * 32) * 64];
    #pragma unroll
    for (int j = 0; j < 4; ++j) gload16(wsrc + (size_t)j * 8 * KPAD, dst + j * 8 * 64);
  }
  __syncthreads();  // covers hT/x0pk ds-writes AND tile0 (vmcnt0+lgkmcnt0)

  union HF { u32 u[4]; half8 h; us8 s; };
  int tt = 0;
  for (int t = 0; t < HC2; ++t) {
    HF hf2[8][2];  // h fragments for hc = 2t, 2t+1 (reused across all f)
    #pragma unroll
    for (int m = 0; m < 8; ++m)
      #pragma unroll
      for (int c = 0; c < 2; ++c)
        hf2[m][c].s = *(const us8*)(&hT[m >> 1][(m & 1) * 16 + l15][(2 * t + c) * 32 + g * 8]);
    for (int f = 0; f < 39; ++f, ++tt) {
      const int buf = tt & 1;
      const bool more = (tt + 1 < NT);
      if (more) {  // issue next tile's 4 loads into buf^1 (per-wave private rows)
        const int nf = (f + 1 < 39) ? f + 1 : 0;
        const int ntp = (f + 1 < 39) ? t : t + 1;
        const int koff = nf * HPAD + ntp * 64;
        u16* dst = &wtile[buf ^ 1][(w * 32) * 64];
        #pragma unroll
        for (int j = 0; j < 4; ++j)
          gload16(wsrc + (size_t)j * 8 * KPAD + koff, dst + j * 8 * 64);
        wait_vm4();  // tile t's 4 loads (oldest) retired; t+1's stay in flight
      } else {
        wait_vm0();  // final tile: drain
      }
      u32 xs[8];
      #pragma unroll
      for (int m = 0; m < 8; ++m) xs[m] = x0pk[m >> 1][(m & 1) * 16 + l15][f];
      #pragma unroll
      for (int c = 0; c < 2; ++c) {
        const int off = (c * 32 + g * 8) ^ xorm;
        HF b0, b1;
        b0.s = *(const us8*)(&wtile[buf][rB0 + off]);
        b1.s = *(const us8*)(&wtile[buf][rB0 + 16 * 64 + off]);
        #pragma unroll
        for (int m = 0; m < 8; ++m) {
          HF a;
          #pragma unroll
          for (int i = 0; i < 4; ++i) a.u[i] = pkmul(hf2[m][c].u[i], xs[m]);
          acc[m][0] = __builtin_amdgcn_mfma_f32_16x16x32_f16(a.h, b0.h, acc[m][0], 0, 0, 0);
          acc[m][1] = __builtin_amdgcn_mfma_f32_16x16x32_f16(a.h, b1.h, acc[m][1], 0, 0, 0);
        }
      }
      // no barrier: wtile rows are wave-private; hT/x0pk are read-only
    }
  }

  // ---- epilogue: relu(acc+bias); o<128 -> h for next layer; else d-sums
  float bv[2];
  #pragma unroll
  for (int nt = 0; nt < 2; ++nt) bv[nt] = bias[w * 32 + nt * 16 + l15];

  if (LAYER < 2 && w < 4) {  // h half (o in [0,128))
    #pragma unroll
    for (int m = 0; m < 8; ++m)
      #pragma unroll
      for (int nt = 0; nt < 2; ++nt) {
        int o = w * 32 + nt * 16 + l15;
        #pragma unroll
        for (int r = 0; r < 4; ++r) {
          int row = m * 16 + g * 4 + r;  // C/D: row=(lane>>4)*4+reg, col=lane&15
          int s = row >> 5, d = row & 31;
          float v = fmaxf(acc[m][nt][r] + bv[nt], 0.f);
          hout[(((bbase + s) * 32 + d) << 7) + o] = f32_to_f16u(v);
        }
      }
  } else {  // finals: sum over d per sample, store fsum[b][j]
    #pragma unroll
    for (int nt = 0; nt < 2; ++nt) {
      float sub[4] = {0.f, 0.f, 0.f, 0.f};
      #pragma unroll
      for (int m = 0; m < 8; ++m)
        #pragma unroll
        for (int r = 0; r < 4; ++r)
          sub[m >> 1] += fmaxf(acc[m][nt][r] + bv[nt], 0.f);
      #pragma unroll
      for (int s = 0; s < 4; ++s) {
        sub[s] += __shfl_xor(sub[s], 16);
        sub[s] += __shfl_xor(sub[s], 32);
      }
      if (lane < 16) {
        int o = w * 32 + nt * 16 + l15;
        int j = (LAYER == 0) ? (o - 128) : ((LAYER == 1) ? o : (256 + o));
        #pragma unroll
        for (int s = 0; s < 4; ++s) fsum[(bbase + s) * 512 + j] = sub[s];
      }
    }
  }
}

// ---------------- finalize: out[b] = fc_b + sum_j fsum[b][j]*fc_w[j] ----------
__global__ void finalize(const float* __restrict__ fsum, const float* __restrict__ fc_w,
                         const float* __restrict__ fc_b, float* __restrict__ out) {
  int b = blockIdx.x;
  int lane = threadIdx.x;  // 64
  const float* fs = fsum + (size_t)b * 512;
  float s = 0.f;
  #pragma unroll
  for (int k = 0; k < 8; ++k) {
    int j = k * 64 + lane;
    s += fs[j] * fc_w[j];
  }
  #pragma unroll
  for (int off = 32; off; off >>= 1) s += __shfl_xor(s, off);
  if (lane == 0) out[b] = s + fc_b[0];
}

extern "C" void kernel_launch(void* const* d_in, const int* in_sizes, int n_in,
                              void* d_out, int out_size, void* d_ws, size_t ws_size,
                              hipStream_t stream) {
  const float* x = (const float*)d_in[0];
  const float* W0 = (const float*)d_in[1];
  const float* b0 = (const float*)d_in[2];
  const float* W1 = (const float*)d_in[3];
  const float* b1 = (const float*)d_in[4];
  const float* W2 = (const float*)d_in[5];
  const float* b2 = (const float*)d_in[6];
  const float* fc_w = (const float*)d_in[7];
  const float* fc_b = (const float*)d_in[8];
  float* out = (float*)d_out;

  char* ws = (char*)d_ws;
  size_t oWT0 = 0;
  size_t oWT1 = oWT0 + (size_t)256 * 2496 * 2;
  size_t oWT2 = oWT1 + (size_t)256 * 4992 * 2;
  size_t oH = oWT2 + (size_t)256 * 4992 * 2;
  size_t oFS = oH + (size_t)1024 * 32 * 128 * 2;
  u16* WT0 = (u16*)(ws + oWT0);
  u16* WT1 = (u16*)(ws + oWT1);
  u16* WT2 = (u16*)(ws + oWT2);
  u16* hbuf = (u16*)(ws + oH);
  float* fsum = (float*)(ws + oFS);

  prep_wt<<<1560, 256, 0, stream>>>(W0, W1, W2, WT0, WT1, WT2);
  cin_layer<0><<<256, 512, 0, stream>>>(x, nullptr, WT0, b0, hbuf, fsum);
  cin_layer<1><<<256, 512, 0, stream>>>(x, hbuf, WT1, b1, hbuf, fsum);
  cin_layer<2><<<256, 512, 0, stream>>>(x, hbuf, WT2, b2, nullptr, fsum);
  finalize<<<1024, 64, 0, stream>>>(fsum, fc_w, fc_b, out);
}